// Round 14
// baseline (203.668 us; speedup 1.0000x reference)
//
#include <hip/hip_runtime.h>
#include <math.h>

#define BB 64
#define TT 128
#define NN 64
#define HH 64
#define EE 128
#define KK 7
#define GG 192  // 3*H

typedef _Float16 half2_t __attribute__((ext_vector_type(2)));

__device__ __forceinline__ float sigmoidf_(float x){ return 1.f/(1.f+expf(-x)); }
__device__ __forceinline__ float fsig_(float x){
  return __builtin_amdgcn_rcpf(1.f + __builtin_amdgcn_exp2f(-1.44269504f * x));
}
__device__ __forceinline__ float ftanh_(float x){
  return fmaf(-2.f, __builtin_amdgcn_rcpf(1.f + __builtin_amdgcn_exp2f(2.88539008f * x)), 1.f);
}

#define PIPE_BARRIER() asm volatile("s_waitcnt lgkmcnt(0)\ns_barrier" ::: "memory")
#define LGKM0() asm volatile("s_waitcnt lgkmcnt(0)" ::: "memory")

__device__ __forceinline__ void loadrow_(float* d, const float* src){
  const float4* p = (const float4*)src;
  #pragma unroll
  for (int i = 0; i < 16; ++i) {
    float4 v = p[i];
    d[4*i] = v.x; d[4*i+1] = v.y; d[4*i+2] = v.z; d[4*i+3] = v.w;
  }
}
__device__ __forceinline__ void loadroww_(half2_t* d, const float* src){
  const float4* p = (const float4*)src;
  #pragma unroll
  for (int i = 0; i < 16; ++i) {
    float4 v = p[i];
    d[2*i]   = half2_t{(_Float16)v.x, (_Float16)v.y};
    d[2*i+1] = half2_t{(_Float16)v.z, (_Float16)v.w};
  }
}
// read 64 f16 (128B) from LDS as 32 packed pairs (uniform-address b128 broadcast)
__device__ __forceinline__ void load_h16_(const _Float16* hs, half2_t* hp){
  const float4* s4 = (const float4*)hs;
  #pragma unroll
  for (int j = 0; j < 8; ++j) {
    float4 v = s4[j];
    const half2_t* q = (const half2_t*)&v;
    hp[4*j] = q[0]; hp[4*j+1] = q[1]; hp[4*j+2] = q[2]; hp[4*j+3] = q[3];
  }
}
// 3-row matvec via v_dot2_f32_f16 (fp32 accumulate)
__device__ __forceinline__ void mvdot3_(const half2_t* hp, const half2_t* w0,
                                        const half2_t* w1, const half2_t* w2,
                                        float& a0, float& a1, float& a2){
  #pragma unroll
  for (int i = 0; i < 32; ++i) {
    a0 = __builtin_amdgcn_fdot2(hp[i], w0[i], a0, false);
    a1 = __builtin_amdgcn_fdot2(hp[i], w1[i], a1, false);
    a2 = __builtin_amdgcn_fdot2(hp[i], w2[i], a2, false);
  }
}

// Conv1d (N->N, K=7, pad same) + SELU + fused s1/s2 projection. [unchanged R12]
__global__ void conv_s12_kernel(const float* __restrict__ x, const float* __restrict__ w,
                                const float* __restrict__ bias, const float* __restrict__ Ww,
                                float* __restrict__ c_nt, float* __restrict__ c_btn,
                                float* __restrict__ s1, float* __restrict__ s2) {
  const int og = blockIdx.x, b = blockIdx.y, t = threadIdx.x;
  const int o0 = og * 8;
  __shared__ __align__(16) float xs[NN][TT + 1];
  __shared__ __align__(16) float ws[NN * KK][8];
  __shared__ __align__(16) float cs[8][TT];
  for (int idx = t; idx < TT * NN; idx += 128) {
    int tt = idx >> 6, nn = idx & 63;
    xs[nn][tt] = x[(size_t)(b * TT + tt) * NN + nn];
  }
  for (int idx = t; idx < NN * KK * 8; idx += 128) {
    int oo = idx & 7, ik = idx >> 3;
    ws[ik][oo] = w[(size_t)(o0 + oo) * (NN * KK) + ik];
  }
  __syncthreads();
  float acc[8];
  #pragma unroll
  for (int oo = 0; oo < 8; ++oo) acc[oo] = bias[o0 + oo];
  for (int i = 0; i < NN; ++i) {
    #pragma unroll
    for (int k = 0; k < KK; ++k) {
      int tt = t + k - 3;
      if (tt >= 0 && tt < TT) {
        float xv = xs[i][tt];
        const float* wp = &ws[i * KK + k][0];
        float4 w0 = *(const float4*)wp;
        float4 w1 = *(const float4*)(wp + 4);
        acc[0] += xv * w0.x; acc[1] += xv * w0.y; acc[2] += xv * w0.z; acc[3] += xv * w0.w;
        acc[4] += xv * w1.x; acc[5] += xv * w1.y; acc[6] += xv * w1.z; acc[7] += xv * w1.w;
      }
    }
  }
  const float alpha = 1.6732632423543772f, scale = 1.0507009873554805f;
  #pragma unroll
  for (int oo = 0; oo < 8; ++oo) {
    float a = acc[oo];
    float r = a > 0.f ? scale * a : scale * alpha * expm1f(a);
    int o = o0 + oo;
    c_nt[((size_t)b * NN + o) * TT + t] = r;
    c_btn[((size_t)b * TT + t) * NN + o] = r;
    cs[oo][t] = r;
  }
  __syncthreads();
  const float* w1 = Ww + (size_t)t * (2 * TT);
  const float* w2 = w1 + TT;
  float a1[8], a2l[8];
  #pragma unroll
  for (int r = 0; r < 8; ++r) { a1[r] = 0.f; a2l[r] = 0.f; }
  #pragma unroll 2
  for (int k = 0; k < TT; k += 4) {
    float4 wv1 = *(const float4*)(w1 + k);
    float4 wv2 = *(const float4*)(w2 + k);
    #pragma unroll
    for (int r = 0; r < 8; ++r) {
      float4 cv = *(const float4*)&cs[r][k];
      a1[r]  += cv.x * wv1.x + cv.y * wv1.y + cv.z * wv1.z + cv.w * wv1.w;
      a2l[r] += cv.x * wv2.x + cv.y * wv2.y + cv.z * wv2.z + cv.w * wv2.w;
    }
  }
  #pragma unroll
  for (int r = 0; r < 8; ++r) {
    s1[((size_t)b * NN + o0 + r) * EE + t] = a1[r];
    s2[((size_t)b * NN + o0 + r) * EE + t] = a2l[r];
  }
}

// Fused GAT + 8-wave chain + heads. One block per batch, 512 threads.
// Pre-phase: stage s1/s2/c_nt -> e + softmax (8 waves x 8 rows) -> PV -> hmph (f16 LDS,
// chunk-XOR swizzled). Chain: R7/R12 structure; wave 7 reads hmph directly (no mbuf,
// no global hmp round-trip).
__global__ __launch_bounds__(512, 1)
void gat_chain8(const float* __restrict__ s1, const float* __restrict__ s2,
                const float* __restrict__ bw, const float* __restrict__ Wa,
                const float* __restrict__ ba, const float* __restrict__ c_nt,
                const float* __restrict__ c_btn,
                const float* __restrict__ We_ih, const float* __restrict__ be_ih,
                const float* __restrict__ We_hh, const float* __restrict__ be_hh,
                const float* __restrict__ Wm_ih, const float* __restrict__ bm_ih,
                const float* __restrict__ Wm_hh, const float* __restrict__ bm_hh,
                const float* __restrict__ Wd_ih, const float* __restrict__ bd_ih,
                const float* __restrict__ Wd_hh, const float* __restrict__ bd_hh,
                const float* __restrict__ W_dec, const float* __restrict__ b_dec,
                const float* __restrict__ W_p1, const float* __restrict__ b_p1,
                const float* __restrict__ W_p2, const float* __restrict__ b_p2,
                float* __restrict__ recon, float* __restrict__ pred) {
  const int b = blockIdx.x, tid = threadIdx.x, wid = tid >> 6, g = tid & 63;
  // ---- GAT LDS (dead after pre-phase except hmph) ----
  __shared__ __align__(16) float s2s[NN][EE + 1];    // s2 + bw
  __shared__ __align__(16) float s1b[NN][EE];
  __shared__ __align__(16) float csn[NN][TT + 4];    // c_nt rows, pad->16B-aligned
  __shared__ __align__(16) float attb[NN][NN];
  __shared__ __align__(16) float wasl[EE];
  __shared__ __align__(16) _Float16 hmph[TT][NN];    // hmp f16, chunk-swizzled
  // ---- chain LDS ----
  __shared__ __align__(16) _Float16 cbuf[2][HH];
  __shared__ __align__(16) _Float16 h1h[2][HH], h2h[2][HH], h3h[2][HH];
  __shared__ __align__(16) float h3f[2][HH];
  __shared__ __align__(16) float q1[2][GG], q2a[2][GG], q2b[2][GG], q3[2][GG];
  __shared__ __align__(16) float h0s[HH], ps[HH];

  // ================= GAT pre-phase =================
  for (int idx = tid; idx < NN * EE; idx += 512) {
    int j = idx >> 7, e = idx & 127;
    s2s[j][e] = s2[((size_t)b * NN + j) * EE + e] + bw[e];
  }
  for (int idx = tid; idx < NN * EE; idx += 512) {
    int j = idx >> 7, e = idx & 127;
    s1b[j][e] = s1[((size_t)b * NN + j) * EE + e];
  }
  for (int idx = tid; idx < NN * TT; idx += 512) {
    int n = idx >> 7, t = idx & 127;
    csn[n][t] = c_nt[((size_t)b * NN + n) * TT + t];
  }
  if (tid < EE) wasl[tid] = Wa[tid];
  __syncthreads();

  const float ba0 = ba[0];
  #pragma unroll
  for (int pass = 0; pass < 8; ++pass) {
    const int i = pass * 8 + wid;
    float acc = 0.f;
    #pragma unroll 8
    for (int e = 0; e < EE; ++e) {
      float v = s1b[i][e] + s2s[g][e];
      v = v > 0.f ? v : 0.2f * v;
      acc += wasl[e] * v;
    }
    float ej = acc + ba0;
    float mx = ej;
    for (int off = 32; off >= 1; off >>= 1) mx = fmaxf(mx, __shfl_xor(mx, off));
    float ex = __builtin_amdgcn_exp2f(1.44269504f * (ej - mx));
    float sm = ex;
    for (int off = 32; off >= 1; off >>= 1) sm += __shfl_xor(sm, off);
    attb[i][g] = ex / sm;
  }
  __syncthreads();

  // PV -> hmph[t][iphys], chunk(8-elem)-XOR swizzle on i to cut write conflicts
  for (int it = tid; it < NN * TT; it += 512) {
    const int i = it >> 7, t = it & 127;
    float acc = 0.f;
    #pragma unroll 8
    for (int j = 0; j < NN; ++j) acc += attb[i][j] * csn[j][t];
    float hv = sigmoidf_(acc);
    int iphys = (i & 7) | ((((i >> 3) ^ (t & 7)) & 7) << 3);
    hmph[t][iphys] = (_Float16)hv;
  }

  // ================= chain =================
  half2_t wa[32], wb[32], wc[32];
  float wdec[64];
  float b0 = 0.f, b1 = 0.f, b2 = 0.f;
  float e0 = 0.f, e1 = 0.f, e2 = 0.f;
  if (wid == 0) {
    loadroww_(wa, We_hh + (size_t)g * HH);
    loadroww_(wb, We_hh + (size_t)(g + 64) * HH);
    loadroww_(wc, We_hh + (size_t)(g + 128) * HH);
    b0 = be_hh[g]; b1 = be_hh[64 + g]; b2 = be_hh[128 + g];
  } else if (wid == 1) {
    loadroww_(wa, Wm_hh + (size_t)g * HH);
    loadroww_(wb, Wm_hh + (size_t)(g + 64) * HH);
    loadroww_(wc, Wm_hh + (size_t)(g + 128) * HH);
    b0 = bm_hh[g]; b1 = bm_hh[64 + g]; b2 = bm_hh[128 + g];
  } else if (wid == 2) {
    loadroww_(wa, Wd_hh + (size_t)g * HH);
    loadroww_(wb, Wd_hh + (size_t)(g + 64) * HH);
    loadroww_(wc, Wd_hh + (size_t)(g + 128) * HH);
    b0 = bd_hh[g]; b1 = bd_hh[64 + g]; b2 = bd_hh[128 + g];
    e0 = bd_ih[g]; e1 = bd_ih[64 + g]; e2 = bd_ih[128 + g];
  } else if (wid == 3) {
    loadrow_(wdec, W_dec + (size_t)g * HH);
    b0 = b_dec[g];
  } else if (wid == 4) {           // Wm_ih [192][128] cols 0..63
    loadroww_(wa, Wm_ih + (size_t)g * 128);
    loadroww_(wb, Wm_ih + (size_t)(g + 64) * 128);
    loadroww_(wc, Wm_ih + (size_t)(g + 128) * 128);
  } else if (wid == 5) {           // Wd_ih [192][64]
    loadroww_(wa, Wd_ih + (size_t)g * HH);
    loadroww_(wb, Wd_ih + (size_t)(g + 64) * HH);
    loadroww_(wc, Wd_ih + (size_t)(g + 128) * HH);
  } else if (wid == 6) {           // We_ih [192][64]
    loadroww_(wa, We_ih + (size_t)g * HH);
    loadroww_(wb, We_ih + (size_t)(g + 64) * HH);
    loadroww_(wc, We_ih + (size_t)(g + 128) * HH);
    b0 = be_ih[g]; b1 = be_ih[64 + g]; b2 = be_ih[128 + g];
  } else {                         // Wm_ih cols 64..127
    loadroww_(wa, Wm_ih + (size_t)g * 128 + 64);
    loadroww_(wb, Wm_ih + (size_t)(g + 64) * 128 + 64);
    loadroww_(wc, Wm_ih + (size_t)(g + 128) * 128 + 64);
    b0 = bm_ih[g]; b1 = bm_ih[64 + g]; b2 = bm_ih[128 + g];
  }

  if (wid == 0) {
    h1h[0][g] = (_Float16)0.f; h1h[1][g] = (_Float16)0.f;
    h2h[0][g] = (_Float16)0.f; h2h[1][g] = (_Float16)0.f;
    h3h[0][g] = (_Float16)0.f; h3h[1][g] = (_Float16)0.f;
  }
  const float* cb = c_btn + (size_t)b * TT * NN + g;
  float pf0 = 0.f, pf1 = 0.f;
  if (wid == 6) {
    cbuf[0][g] = (_Float16)cb[0]; cbuf[1][g] = (_Float16)cb[NN];
    pf0 = cb[2 * NN]; pf1 = cb[3 * NN];
  }
  if (wid <= 2) __builtin_amdgcn_s_setprio(1);   // favor the rec critical chain
  __syncthreads();

  float hown = 0.f;
  for (int ph = 0; ph < TT + 6; ++ph) {
    const int pw = ph & 1, pr = pw ^ 1;
    if (wid == 6) {                 // gi1 = We_ih @ c[t] + be_ih, t = ph
      int t = ph;
      if (t < TT) {
        half2_t hp[32]; load_h16_(&cbuf[pw][0], hp);
        if (t + 2 < TT) cbuf[pw][g] = (_Float16)(pw ? pf1 : pf0);
        float a0 = b0, a1 = b1, a2 = b2;
        if (t + 4 < TT) { float nv = cb[(size_t)(t + 4) * NN]; if (pw) pf1 = nv; else pf0 = nv; }
        mvdot3_(hp, wa, wb, wc, a0, a1, a2);
        q1[pw][g] = a0; q1[pw][64 + g] = a1; q1[pw][128 + g] = a2;
      }
    } else if (wid == 0) {          // rec1, t = ph-1
      int t = ph - 1;
      if (t >= 0 && t < TT) {
        half2_t hp[32]; load_h16_(&h1h[pr][0], hp);
        float a0 = b0, a1 = b1, a2 = b2;
        mvdot3_(hp, wa, wb, wc, a0, a1, a2);
        float r = fsig_(q1[pr][g] + a0), z = fsig_(q1[pr][64 + g] + a1);
        float n = ftanh_(q1[pr][128 + g] + r * a2);
        hown = fmaf(z, hown - n, n);
        h1h[pw][g] = (_Float16)hown;
      }
    } else if (wid == 4) {          // q2a = Wm_ih[:,:64] @ h1[t], t = ph-2
      int t = ph - 2;
      if (t >= 0 && t < TT) {
        half2_t hp[32]; load_h16_(&h1h[pr][0], hp);
        float a0 = 0.f, a1 = 0.f, a2 = 0.f;
        mvdot3_(hp, wa, wb, wc, a0, a1, a2);
        q2a[pw][g] = a0; q2a[pw][64 + g] = a1; q2a[pw][128 + g] = a2;
      }
    } else if (wid == 7) {          // q2b = Wm_ih[:,64:] @ hmp[t] + bm_ih, t = ph-2
      int t = ph - 2;
      if (t >= 0 && t < TT) {
        half2_t hp[32];
        const int sw = t & 7;
        const float4* s4 = (const float4*)&hmph[t][0];
        #pragma unroll
        for (int j = 0; j < 8; ++j) {
          float4 v = s4[j ^ sw];
          const half2_t* q = (const half2_t*)&v;
          hp[4*j] = q[0]; hp[4*j+1] = q[1]; hp[4*j+2] = q[2]; hp[4*j+3] = q[3];
        }
        float a0 = b0, a1 = b1, a2 = b2;
        mvdot3_(hp, wa, wb, wc, a0, a1, a2);
        q2b[pw][g] = a0; q2b[pw][64 + g] = a1; q2b[pw][128 + g] = a2;
      }
    } else if (wid == 1) {          // rec2, t = ph-3
      int t = ph - 3;
      if (t >= 0 && t < TT) {
        half2_t hp[32]; load_h16_(&h2h[pr][0], hp);
        float a0 = b0, a1 = b1, a2 = b2;
        mvdot3_(hp, wa, wb, wc, a0, a1, a2);
        float gr = q2a[pr][g] + q2b[pr][g];
        float gz = q2a[pr][64 + g] + q2b[pr][64 + g];
        float gn = q2a[pr][128 + g] + q2b[pr][128 + g];
        float r = fsig_(gr + a0), z = fsig_(gz + a1), n = ftanh_(gn + r * a2);
        hown = fmaf(z, hown - n, n);
        h2h[pw][g] = (_Float16)hown;
      }
    } else if (wid == 5) {          // q3 = Wd_ih @ h2[t], t = ph-4
      int t = ph - 4;
      if (t >= 0 && t < TT) {
        half2_t hp[32]; load_h16_(&h2h[pr][0], hp);
        float a0 = 0.f, a1 = 0.f, a2 = 0.f;
        mvdot3_(hp, wa, wb, wc, a0, a1, a2);
        q3[pw][g] = a0; q3[pw][64 + g] = a1; q3[pw][128 + g] = a2;
      }
    } else if (wid == 2) {          // rec3, t = ph-5
      int t = ph - 5;
      if (t >= 0 && t < TT) {
        half2_t hp[32]; load_h16_(&h3h[pr][0], hp);
        float a0 = b0, a1 = b1, a2 = b2;
        mvdot3_(hp, wa, wb, wc, a0, a1, a2);
        float r = fsig_(q3[pr][g] + e0 + a0), z = fsig_(q3[pr][64 + g] + e1 + a1);
        float n = ftanh_(q3[pr][128 + g] + e2 + r * a2);
        hown = fmaf(z, hown - n, n);
        h3h[pw][g] = (_Float16)hown;
        h3f[pw][g] = hown;
        if (t == 0) h0s[g] = hown;
      }
    } else {                        // wid==3: recon = W_dec @ h3[t] + b_dec, t = ph-6
      int t = ph - 6;
      if (t >= 0) {
        const float4* h4 = (const float4*)&h3f[pr][0];
        float a0 = b0, a1 = 0.f;
        #pragma unroll
        for (int i = 0; i < 8; ++i) {
          float4 hv = h4[2 * i], hw = h4[2 * i + 1];
          a0 = fmaf(hv.x, wdec[8*i],   fmaf(hv.y, wdec[8*i+1], fmaf(hv.z, wdec[8*i+2], fmaf(hv.w, wdec[8*i+3], a0))));
          a1 = fmaf(hw.x, wdec[8*i+4], fmaf(hw.y, wdec[8*i+5], fmaf(hw.z, wdec[8*i+6], fmaf(hw.w, wdec[8*i+7], a1))));
        }
        recon[((size_t)b * TT + t) * NN + g] = a0 + a1;
      }
    }
    PIPE_BARRIER();
  }

  // pred head (wave 0 only)
  if (wid == 0) {
    float w1r[64]; loadrow_(w1r, W_p1 + (size_t)g * HH);
    const float4* h4 = (const float4*)&h0s[0];
    float a = b_p1[g];
    #pragma unroll
    for (int i = 0; i < 16; ++i) {
      float4 hv = h4[i];
      a = fmaf(hv.x, w1r[4*i], fmaf(hv.y, w1r[4*i+1], fmaf(hv.z, w1r[4*i+2], fmaf(hv.w, w1r[4*i+3], a))));
    }
    ps[g] = fmaxf(a, 0.f);
    LGKM0();
    float w2r[64]; loadrow_(w2r, W_p2 + (size_t)g * HH);
    const float4* p4 = (const float4*)&ps[0];
    float c2 = b_p2[g];
    #pragma unroll
    for (int i = 0; i < 16; ++i) {
      float4 pv = p4[i];
      c2 = fmaf(pv.x, w2r[4*i], fmaf(pv.y, w2r[4*i+1], fmaf(pv.z, w2r[4*i+2], fmaf(pv.w, w2r[4*i+3], c2))));
    }
    pred[(size_t)b * NN + g] = c2;
  }
}

extern "C" void kernel_launch(void* const* d_in, const int* in_sizes, int n_in,
                              void* d_out, int out_size, void* d_ws, size_t ws_size,
                              hipStream_t stream) {
  const float* x      = (const float*)d_in[0];
  const float* conv_w = (const float*)d_in[2];
  const float* conv_b = (const float*)d_in[3];
  const float* We_ih  = (const float*)d_in[4];
  const float* We_hh  = (const float*)d_in[5];
  const float* be_ih  = (const float*)d_in[6];
  const float* be_hh  = (const float*)d_in[7];
  const float* Ww     = (const float*)d_in[8];
  const float* bw     = (const float*)d_in[9];
  const float* Wa     = (const float*)d_in[10];
  const float* ba     = (const float*)d_in[11];
  const float* Wm_ih  = (const float*)d_in[12];
  const float* Wm_hh  = (const float*)d_in[13];
  const float* bm_ih  = (const float*)d_in[14];
  const float* bm_hh  = (const float*)d_in[15];
  const float* Wd_ih  = (const float*)d_in[16];
  const float* Wd_hh  = (const float*)d_in[17];
  const float* bd_ih  = (const float*)d_in[18];
  const float* bd_hh  = (const float*)d_in[19];
  const float* W_dec  = (const float*)d_in[20];
  const float* b_dec  = (const float*)d_in[21];
  const float* W_p1   = (const float*)d_in[22];
  const float* b_p1   = (const float*)d_in[23];
  const float* W_p2   = (const float*)d_in[24];
  const float* b_p2   = (const float*)d_in[25];
  float* out = (float*)d_out;

  float* wsf   = (float*)d_ws;
  float* c_nt  = wsf;                 // B*N*T    = 524288
  float* c_btn = c_nt  + 524288;      // B*T*N    = 524288
  float* s1    = c_btn + 524288;      // B*N*E    = 524288
  float* s2    = s1    + 524288;      // B*N*E    = 524288

  conv_s12_kernel<<<dim3(8, BB), 128, 0, stream>>>(x, conv_w, conv_b, Ww,
                                                   c_nt, c_btn, s1, s2);
  gat_chain8<<<BB, 512, 0, stream>>>(s1, s2, bw, Wa, ba, c_nt, c_btn,
                                     We_ih, be_ih, We_hh, be_hh,
                                     Wm_ih, bm_ih, Wm_hh, bm_hh,
                                     Wd_ih, bd_ih, Wd_hh, bd_hh,
                                     W_dec, b_dec, W_p1, b_p1, W_p2, b_p2,
                                     out, out + BB * TT * NN);
}

// Round 15
// 177.621 us; speedup vs baseline: 1.1466x; 1.1466x over previous
//
#include <hip/hip_runtime.h>
#include <math.h>

#define BB 64
#define TT 128
#define NN 64
#define HH 64
#define EE 128
#define KK 7
#define GG 192  // 3*H

typedef _Float16 half2_t __attribute__((ext_vector_type(2)));

__device__ __forceinline__ float sigmoidf_(float x){ return 1.f/(1.f+expf(-x)); }
__device__ __forceinline__ float fsig_(float x){
  return __builtin_amdgcn_rcpf(1.f + __builtin_amdgcn_exp2f(-1.44269504f * x));
}
__device__ __forceinline__ float ftanh_(float x){
  return fmaf(-2.f, __builtin_amdgcn_rcpf(1.f + __builtin_amdgcn_exp2f(2.88539008f * x)), 1.f);
}

#define PIPE_BARRIER() asm volatile("s_waitcnt lgkmcnt(0)\ns_barrier" ::: "memory")
#define LGKM0() asm volatile("s_waitcnt lgkmcnt(0)" ::: "memory")

__device__ __forceinline__ void loadrow_(float* d, const float* src){
  const float4* p = (const float4*)src;
  #pragma unroll
  for (int i = 0; i < 16; ++i) {
    float4 v = p[i];
    d[4*i] = v.x; d[4*i+1] = v.y; d[4*i+2] = v.z; d[4*i+3] = v.w;
  }
}
__device__ __forceinline__ void loadroww_(half2_t* d, const float* src){
  const float4* p = (const float4*)src;
  #pragma unroll
  for (int i = 0; i < 16; ++i) {
    float4 v = p[i];
    d[2*i]   = half2_t{(_Float16)v.x, (_Float16)v.y};
    d[2*i+1] = half2_t{(_Float16)v.z, (_Float16)v.w};
  }
}
// read 64 f16 (128B) from LDS as 32 packed pairs (uniform-address b128 broadcast)
__device__ __forceinline__ void load_h16_(const _Float16* hs, half2_t* hp){
  const float4* s4 = (const float4*)hs;
  #pragma unroll
  for (int j = 0; j < 8; ++j) {
    float4 v = s4[j];
    const half2_t* q = (const half2_t*)&v;
    hp[4*j] = q[0]; hp[4*j+1] = q[1]; hp[4*j+2] = q[2]; hp[4*j+3] = q[3];
  }
}
// 3-row matvec via v_dot2_f32_f16 (fp32 accumulate)
__device__ __forceinline__ void mvdot3_(const half2_t* hp, const half2_t* w0,
                                        const half2_t* w1, const half2_t* w2,
                                        float& a0, float& a1, float& a2){
  #pragma unroll
  for (int i = 0; i < 32; ++i) {
    a0 = __builtin_amdgcn_fdot2(hp[i], w0[i], a0, false);
    a1 = __builtin_amdgcn_fdot2(hp[i], w1[i], a1, false);
    a2 = __builtin_amdgcn_fdot2(hp[i], w2[i], a2, false);
  }
}

// Conv1d (N->N, K=7, pad same) + SELU + fused s1/s2 projection. [unchanged R12]
__global__ void conv_s12_kernel(const float* __restrict__ x, const float* __restrict__ w,
                                const float* __restrict__ bias, const float* __restrict__ Ww,
                                float* __restrict__ c_nt, float* __restrict__ c_btn,
                                float* __restrict__ s1, float* __restrict__ s2) {
  const int og = blockIdx.x, b = blockIdx.y, t = threadIdx.x;
  const int o0 = og * 8;
  __shared__ __align__(16) float xs[NN][TT + 1];
  __shared__ __align__(16) float ws[NN * KK][8];
  __shared__ __align__(16) float cs[8][TT];
  for (int idx = t; idx < TT * NN; idx += 128) {
    int tt = idx >> 6, nn = idx & 63;
    xs[nn][tt] = x[(size_t)(b * TT + tt) * NN + nn];
  }
  for (int idx = t; idx < NN * KK * 8; idx += 128) {
    int oo = idx & 7, ik = idx >> 3;
    ws[ik][oo] = w[(size_t)(o0 + oo) * (NN * KK) + ik];
  }
  __syncthreads();
  float acc[8];
  #pragma unroll
  for (int oo = 0; oo < 8; ++oo) acc[oo] = bias[o0 + oo];
  for (int i = 0; i < NN; ++i) {
    #pragma unroll
    for (int k = 0; k < KK; ++k) {
      int tt = t + k - 3;
      if (tt >= 0 && tt < TT) {
        float xv = xs[i][tt];
        const float* wp = &ws[i * KK + k][0];
        float4 w0 = *(const float4*)wp;
        float4 w1 = *(const float4*)(wp + 4);
        acc[0] += xv * w0.x; acc[1] += xv * w0.y; acc[2] += xv * w0.z; acc[3] += xv * w0.w;
        acc[4] += xv * w1.x; acc[5] += xv * w1.y; acc[6] += xv * w1.z; acc[7] += xv * w1.w;
      }
    }
  }
  const float alpha = 1.6732632423543772f, scale = 1.0507009873554805f;
  #pragma unroll
  for (int oo = 0; oo < 8; ++oo) {
    float a = acc[oo];
    float r = a > 0.f ? scale * a : scale * alpha * expm1f(a);
    int o = o0 + oo;
    c_nt[((size_t)b * NN + o) * TT + t] = r;
    c_btn[((size_t)b * TT + t) * NN + o] = r;
    cs[oo][t] = r;
  }
  __syncthreads();
  const float* w1 = Ww + (size_t)t * (2 * TT);
  const float* w2 = w1 + TT;
  float a1[8], a2l[8];
  #pragma unroll
  for (int r = 0; r < 8; ++r) { a1[r] = 0.f; a2l[r] = 0.f; }
  #pragma unroll 2
  for (int k = 0; k < TT; k += 4) {
    float4 wv1 = *(const float4*)(w1 + k);
    float4 wv2 = *(const float4*)(w2 + k);
    #pragma unroll
    for (int r = 0; r < 8; ++r) {
      float4 cv = *(const float4*)&cs[r][k];
      a1[r]  += cv.x * wv1.x + cv.y * wv1.y + cv.z * wv1.z + cv.w * wv1.w;
      a2l[r] += cv.x * wv2.x + cv.y * wv2.y + cv.z * wv2.z + cv.w * wv2.w;
    }
  }
  #pragma unroll
  for (int r = 0; r < 8; ++r) {
    s1[((size_t)b * NN + o0 + r) * EE + t] = a1[r];
    s2[((size_t)b * NN + o0 + r) * EE + t] = a2l[r];
  }
}

// GAT v3: 16 rows/block, 512 threads (8 waves -> 2 e-passes, 2 blocks/CU),
// PV writes 16-wide coalesced, att padded [16][65] for conflict-free il-reads.
__global__ __launch_bounds__(512)
void gat_kernel(const float* __restrict__ s1, const float* __restrict__ s2,
                const float* __restrict__ bw, const float* __restrict__ Wa,
                const float* __restrict__ ba, const float* __restrict__ c_nt,
                float* __restrict__ hmp) {
  const int it = blockIdx.x, b = blockIdx.y, tid = threadIdx.x;
  const int i0 = it * 16;
  __shared__ float s2s[NN][EE + 1];
  __shared__ float s1b[16][EE];
  __shared__ float cs[NN][TT + 1];
  __shared__ float was[EE];
  __shared__ float att[16][NN + 1];
  for (int idx = tid; idx < NN * EE; idx += 512) {
    int j = idx >> 7, e = idx & 127;
    s2s[j][e] = s2[((size_t)b * NN + j) * EE + e] + bw[e];
  }
  for (int idx = tid; idx < 16 * EE; idx += 512) {
    int r = idx >> 7, e = idx & 127;
    s1b[r][e] = s1[((size_t)b * NN + i0 + r) * EE + e];
  }
  for (int idx = tid; idx < NN * TT; idx += 512) {
    int j = idx >> 7, t = idx & 127;
    cs[j][t] = c_nt[((size_t)b * NN + j) * TT + t];
  }
  if (tid < EE) was[tid] = Wa[tid];
  __syncthreads();
  const int wv = tid >> 6, j = tid & 63;
  #pragma unroll
  for (int pass = 0; pass < 2; ++pass) {
    const int il = pass * 8 + wv;
    float acc = 0.f;
    #pragma unroll 8
    for (int e = 0; e < EE; ++e) {
      float v = s1b[il][e] + s2s[j][e];
      v = v > 0.f ? v : 0.2f * v;
      acc += was[e] * v;
    }
    float ej = acc + ba[0];
    float mx = ej;
    for (int off = 32; off >= 1; off >>= 1) mx = fmaxf(mx, __shfl_xor(mx, off));
    float ex = __builtin_amdgcn_exp2f(1.44269504f * (ej - mx));
    float sm = ex;
    for (int off = 32; off >= 1; off >>= 1) sm += __shfl_xor(sm, off);
    att[il][j] = ex / sm;
  }
  __syncthreads();
  // PV: il lane-fastest -> 64B coalesced hmp writes; att il-reads conflict-free via +1 pad
  for (int o = tid; o < 16 * TT; o += 512) {
    int il = o & 15, t = o >> 4;
    float acc = 0.f;
    #pragma unroll 8
    for (int jj = 0; jj < NN; ++jj) acc += att[il][jj] * cs[jj][t];
    hmp[((size_t)b * TT + t) * NN + i0 + il] = sigmoidf_(acc);
  }
}

// Fused 8-wave chain + heads. [unchanged R12, measured 112-114 µs]
__global__ __launch_bounds__(512, 1)
void fused_chain8(const float* __restrict__ c_btn, const float* __restrict__ hmp,
                  const float* __restrict__ We_ih, const float* __restrict__ be_ih,
                  const float* __restrict__ We_hh, const float* __restrict__ be_hh,
                  const float* __restrict__ Wm_ih, const float* __restrict__ bm_ih,
                  const float* __restrict__ Wm_hh, const float* __restrict__ bm_hh,
                  const float* __restrict__ Wd_ih, const float* __restrict__ bd_ih,
                  const float* __restrict__ Wd_hh, const float* __restrict__ bd_hh,
                  const float* __restrict__ W_dec, const float* __restrict__ b_dec,
                  const float* __restrict__ W_p1, const float* __restrict__ b_p1,
                  const float* __restrict__ W_p2, const float* __restrict__ b_p2,
                  float* __restrict__ recon, float* __restrict__ pred) {
  const int b = blockIdx.x, tid = threadIdx.x, wid = tid >> 6, g = tid & 63;
  __shared__ __align__(16) _Float16 cbuf[2][HH], mbuf[2][HH];
  __shared__ __align__(16) _Float16 h1h[2][HH], h2h[2][HH], h3h[2][HH];
  __shared__ __align__(16) float h3f[2][HH];
  __shared__ __align__(16) float q1[2][GG], q2a[2][GG], q2b[2][GG], q3[2][GG];
  __shared__ __align__(16) float h0s[HH], ps[HH];

  half2_t wa[32], wb[32], wc[32];
  float wdec[64];
  float b0 = 0.f, b1 = 0.f, b2 = 0.f;
  float e0 = 0.f, e1 = 0.f, e2 = 0.f;
  if (wid == 0) {
    loadroww_(wa, We_hh + (size_t)g * HH);
    loadroww_(wb, We_hh + (size_t)(g + 64) * HH);
    loadroww_(wc, We_hh + (size_t)(g + 128) * HH);
    b0 = be_hh[g]; b1 = be_hh[64 + g]; b2 = be_hh[128 + g];
  } else if (wid == 1) {
    loadroww_(wa, Wm_hh + (size_t)g * HH);
    loadroww_(wb, Wm_hh + (size_t)(g + 64) * HH);
    loadroww_(wc, Wm_hh + (size_t)(g + 128) * HH);
    b0 = bm_hh[g]; b1 = bm_hh[64 + g]; b2 = bm_hh[128 + g];
  } else if (wid == 2) {
    loadroww_(wa, Wd_hh + (size_t)g * HH);
    loadroww_(wb, Wd_hh + (size_t)(g + 64) * HH);
    loadroww_(wc, Wd_hh + (size_t)(g + 128) * HH);
    b0 = bd_hh[g]; b1 = bd_hh[64 + g]; b2 = bd_hh[128 + g];
    e0 = bd_ih[g]; e1 = bd_ih[64 + g]; e2 = bd_ih[128 + g];
  } else if (wid == 3) {
    loadrow_(wdec, W_dec + (size_t)g * HH);
    b0 = b_dec[g];
  } else if (wid == 4) {           // Wm_ih [192][128] cols 0..63
    loadroww_(wa, Wm_ih + (size_t)g * 128);
    loadroww_(wb, Wm_ih + (size_t)(g + 64) * 128);
    loadroww_(wc, Wm_ih + (size_t)(g + 128) * 128);
  } else if (wid == 5) {           // Wd_ih [192][64]
    loadroww_(wa, Wd_ih + (size_t)g * HH);
    loadroww_(wb, Wd_ih + (size_t)(g + 64) * HH);
    loadroww_(wc, Wd_ih + (size_t)(g + 128) * HH);
  } else if (wid == 6) {           // We_ih [192][64]
    loadroww_(wa, We_ih + (size_t)g * HH);
    loadroww_(wb, We_ih + (size_t)(g + 64) * HH);
    loadroww_(wc, We_ih + (size_t)(g + 128) * HH);
    b0 = be_ih[g]; b1 = be_ih[64 + g]; b2 = be_ih[128 + g];
  } else {                         // Wm_ih cols 64..127
    loadroww_(wa, Wm_ih + (size_t)g * 128 + 64);
    loadroww_(wb, Wm_ih + (size_t)(g + 64) * 128 + 64);
    loadroww_(wc, Wm_ih + (size_t)(g + 128) * 128 + 64);
    b0 = bm_ih[g]; b1 = bm_ih[64 + g]; b2 = bm_ih[128 + g];
  }

  if (wid == 0) {
    h1h[0][g] = (_Float16)0.f; h1h[1][g] = (_Float16)0.f;
    h2h[0][g] = (_Float16)0.f; h2h[1][g] = (_Float16)0.f;
    h3h[0][g] = (_Float16)0.f; h3h[1][g] = (_Float16)0.f;
  }
  const float* cb = c_btn + (size_t)b * TT * NN + g;
  const float* hm = hmp   + (size_t)b * TT * NN + g;
  float pf0 = 0.f, pf1 = 0.f;
  if (wid == 6) {
    cbuf[0][g] = (_Float16)cb[0]; cbuf[1][g] = (_Float16)cb[NN];
    pf0 = cb[2 * NN]; pf1 = cb[3 * NN];
  }
  if (wid == 7) {
    mbuf[0][g] = (_Float16)hm[0]; mbuf[1][g] = (_Float16)hm[NN];
    pf0 = hm[2 * NN]; pf1 = hm[3 * NN];
  }
  if (wid <= 2) __builtin_amdgcn_s_setprio(1);   // favor the rec critical chain
  __syncthreads();

  float hown = 0.f;
  for (int ph = 0; ph < TT + 6; ++ph) {
    const int pw = ph & 1, pr = pw ^ 1;
    if (wid == 6) {                 // gi1 = We_ih @ c[t] + be_ih, t = ph
      int t = ph;
      if (t < TT) {
        half2_t hp[32]; load_h16_(&cbuf[pw][0], hp);
        if (t + 2 < TT) cbuf[pw][g] = (_Float16)(pw ? pf1 : pf0);
        float a0 = b0, a1 = b1, a2 = b2;
        if (t + 4 < TT) { float nv = cb[(size_t)(t + 4) * NN]; if (pw) pf1 = nv; else pf0 = nv; }
        mvdot3_(hp, wa, wb, wc, a0, a1, a2);
        q1[pw][g] = a0; q1[pw][64 + g] = a1; q1[pw][128 + g] = a2;
      }
    } else if (wid == 0) {          // rec1, t = ph-1
      int t = ph - 1;
      if (t >= 0 && t < TT) {
        half2_t hp[32]; load_h16_(&h1h[pr][0], hp);
        float a0 = b0, a1 = b1, a2 = b2;
        mvdot3_(hp, wa, wb, wc, a0, a1, a2);
        float r = fsig_(q1[pr][g] + a0), z = fsig_(q1[pr][64 + g] + a1);
        float n = ftanh_(q1[pr][128 + g] + r * a2);
        hown = fmaf(z, hown - n, n);
        h1h[pw][g] = (_Float16)hown;
      }
    } else if (wid == 4) {          // q2a = Wm_ih[:,:64] @ h1[t], t = ph-2
      int t = ph - 2;
      if (t >= 0 && t < TT) {
        half2_t hp[32]; load_h16_(&h1h[pr][0], hp);
        float a0 = 0.f, a1 = 0.f, a2 = 0.f;
        mvdot3_(hp, wa, wb, wc, a0, a1, a2);
        q2a[pw][g] = a0; q2a[pw][64 + g] = a1; q2a[pw][128 + g] = a2;
      }
    } else if (wid == 7) {          // q2b = Wm_ih[:,64:] @ hmp[t] + bm_ih, t = ph-2
      int t = ph - 2;
      if (t >= 0 && t < TT) {
        half2_t hp[32]; load_h16_(&mbuf[pw][0], hp);
        if (t + 2 < TT) mbuf[pw][g] = (_Float16)(pw ? pf1 : pf0);
        float a0 = b0, a1 = b1, a2 = b2;
        if (t + 4 < TT) { float nv = hm[(size_t)(t + 4) * NN]; if (pw) pf1 = nv; else pf0 = nv; }
        mvdot3_(hp, wa, wb, wc, a0, a1, a2);
        q2b[pw][g] = a0; q2b[pw][64 + g] = a1; q2b[pw][128 + g] = a2;
      }
    } else if (wid == 1) {          // rec2, t = ph-3
      int t = ph - 3;
      if (t >= 0 && t < TT) {
        half2_t hp[32]; load_h16_(&h2h[pr][0], hp);
        float a0 = b0, a1 = b1, a2 = b2;
        mvdot3_(hp, wa, wb, wc, a0, a1, a2);
        float gr = q2a[pr][g] + q2b[pr][g];
        float gz = q2a[pr][64 + g] + q2b[pr][64 + g];
        float gn = q2a[pr][128 + g] + q2b[pr][128 + g];
        float r = fsig_(gr + a0), z = fsig_(gz + a1), n = ftanh_(gn + r * a2);
        hown = fmaf(z, hown - n, n);
        h2h[pw][g] = (_Float16)hown;
      }
    } else if (wid == 5) {          // q3 = Wd_ih @ h2[t], t = ph-4
      int t = ph - 4;
      if (t >= 0 && t < TT) {
        half2_t hp[32]; load_h16_(&h2h[pr][0], hp);
        float a0 = 0.f, a1 = 0.f, a2 = 0.f;
        mvdot3_(hp, wa, wb, wc, a0, a1, a2);
        q3[pw][g] = a0; q3[pw][64 + g] = a1; q3[pw][128 + g] = a2;
      }
    } else if (wid == 2) {          // rec3, t = ph-5
      int t = ph - 5;
      if (t >= 0 && t < TT) {
        half2_t hp[32]; load_h16_(&h3h[pr][0], hp);
        float a0 = b0, a1 = b1, a2 = b2;
        mvdot3_(hp, wa, wb, wc, a0, a1, a2);
        float r = fsig_(q3[pr][g] + e0 + a0), z = fsig_(q3[pr][64 + g] + e1 + a1);
        float n = ftanh_(q3[pr][128 + g] + e2 + r * a2);
        hown = fmaf(z, hown - n, n);
        h3h[pw][g] = (_Float16)hown;
        h3f[pw][g] = hown;
        if (t == 0) h0s[g] = hown;
      }
    } else {                        // wid==3: recon = W_dec @ h3[t] + b_dec, t = ph-6
      int t = ph - 6;
      if (t >= 0) {
        const float4* h4 = (const float4*)&h3f[pr][0];
        float a0 = b0, a1 = 0.f;
        #pragma unroll
        for (int i = 0; i < 8; ++i) {
          float4 hv = h4[2 * i], hw = h4[2 * i + 1];
          a0 = fmaf(hv.x, wdec[8*i],   fmaf(hv.y, wdec[8*i+1], fmaf(hv.z, wdec[8*i+2], fmaf(hv.w, wdec[8*i+3], a0))));
          a1 = fmaf(hw.x, wdec[8*i+4], fmaf(hw.y, wdec[8*i+5], fmaf(hw.z, wdec[8*i+6], fmaf(hw.w, wdec[8*i+7], a1))));
        }
        recon[((size_t)b * TT + t) * NN + g] = a0 + a1;
      }
    }
    PIPE_BARRIER();
  }

  // pred head (wave 0 only)
  if (wid == 0) {
    float w1r[64]; loadrow_(w1r, W_p1 + (size_t)g * HH);
    const float4* h4 = (const float4*)&h0s[0];
    float a = b_p1[g];
    #pragma unroll
    for (int i = 0; i < 16; ++i) {
      float4 hv = h4[i];
      a = fmaf(hv.x, w1r[4*i], fmaf(hv.y, w1r[4*i+1], fmaf(hv.z, w1r[4*i+2], fmaf(hv.w, w1r[4*i+3], a))));
    }
    ps[g] = fmaxf(a, 0.f);
    LGKM0();
    float w2r[64]; loadrow_(w2r, W_p2 + (size_t)g * HH);
    const float4* p4 = (const float4*)&ps[0];
    float c2 = b_p2[g];
    #pragma unroll
    for (int i = 0; i < 16; ++i) {
      float4 pv = p4[i];
      c2 = fmaf(pv.x, w2r[4*i], fmaf(pv.y, w2r[4*i+1], fmaf(pv.z, w2r[4*i+2], fmaf(pv.w, w2r[4*i+3], c2))));
    }
    pred[(size_t)b * NN + g] = c2;
  }
}

extern "C" void kernel_launch(void* const* d_in, const int* in_sizes, int n_in,
                              void* d_out, int out_size, void* d_ws, size_t ws_size,
                              hipStream_t stream) {
  const float* x      = (const float*)d_in[0];
  const float* conv_w = (const float*)d_in[2];
  const float* conv_b = (const float*)d_in[3];
  const float* We_ih  = (const float*)d_in[4];
  const float* We_hh  = (const float*)d_in[5];
  const float* be_ih  = (const float*)d_in[6];
  const float* be_hh  = (const float*)d_in[7];
  const float* Ww     = (const float*)d_in[8];
  const float* bw     = (const float*)d_in[9];
  const float* Wa     = (const float*)d_in[10];
  const float* ba     = (const float*)d_in[11];
  const float* Wm_ih  = (const float*)d_in[12];
  const float* Wm_hh  = (const float*)d_in[13];
  const float* bm_ih  = (const float*)d_in[14];
  const float* bm_hh  = (const float*)d_in[15];
  const float* Wd_ih  = (const float*)d_in[16];
  const float* Wd_hh  = (const float*)d_in[17];
  const float* bd_ih  = (const float*)d_in[18];
  const float* bd_hh  = (const float*)d_in[19];
  const float* W_dec  = (const float*)d_in[20];
  const float* b_dec  = (const float*)d_in[21];
  const float* W_p1   = (const float*)d_in[22];
  const float* b_p1   = (const float*)d_in[23];
  const float* W_p2   = (const float*)d_in[24];
  const float* b_p2   = (const float*)d_in[25];
  float* out = (float*)d_out;

  float* wsf   = (float*)d_ws;
  float* c_nt  = wsf;                 // B*N*T    = 524288
  float* c_btn = c_nt  + 524288;      // B*T*N    = 524288
  float* s1    = c_btn + 524288;      // B*N*E    = 524288
  float* s2    = s1    + 524288;      // B*N*E    = 524288
  float* hmp   = s2    + 524288;      // B*T*N    = 524288

  conv_s12_kernel<<<dim3(8, BB), 128, 0, stream>>>(x, conv_w, conv_b, Ww,
                                                   c_nt, c_btn, s1, s2);
  gat_kernel<<<dim3(4, BB), 512, 0, stream>>>(s1, s2, bw, Wa, ba, c_nt, hmp);
  fused_chain8<<<BB, 512, 0, stream>>>(c_btn, hmp,
                                       We_ih, be_ih, We_hh, be_hh,
                                       Wm_ih, bm_ih, Wm_hh, bm_hh,
                                       Wd_ih, bd_ih, Wd_hh, bd_hh,
                                       W_dec, b_dec, W_p1, b_p1, W_p2, b_p2,
                                       out, out + BB * TT * NN);
}